// Round 1
// 311.531 us; speedup vs baseline: 1.0698x; 1.0698x over previous
//
#include <hip/hip_runtime.h>

// ---------------------------------------------------------------------------
// LiteMLA: B=4, N=4096, C=1024, D=32, h=32 heads.
//   qkv = x @ W_qkv^T            (16384 x 3072, K=1024)   [relu on q,k cols]
//   per (b,h): vk[d,e] = sum_n Vpad[d,n]*reluK[e,n]   (33x32, reduce N=4096)
//              y[d,n]  = (sum_e vk[d,e]*reluQ[e,n]) / (sum_e vk[32,e]*reluQ[e,n] + eps)
//   out = y @ W_proj^T + b_proj  (16384 x 1024, K=1024)
//
// GEMMs: 256x256 tile, BK=64, 8 waves (512 thr), 128 KiB dynamic LDS,
// 4-phase-per-K-tile schedule (T3+T4): each phase = ds_read quadrant frags
// || 1 half-tile global_load_lds prefetch || 16 MFMA (setprio-wrapped, T5),
// raw s_barrier per phase, vmcnt(6) once per K-tile (loads in flight across
// barriers). LDS slot swizzle (kk*4+kq)^(row&7) applied on the pre-swizzled
// global source + the ds_read address (linear DMA dest). Race-freedom:
//   - all B reads in P1, A reads end P3; every stage into a region is issued
//     after the lgkmcnt(0)+barrier draining that region's readers.
//   - vmcnt(6) at P4 retires exactly through tile g+1's last half (staged P1)
//     before group g+1 reads it.
// Accumulation order identical to previous kernel -> same numerics.
// ---------------------------------------------------------------------------

using us8   = __attribute__((ext_vector_type(8))) unsigned short;
using us4   = __attribute__((ext_vector_type(4))) unsigned short;
using s8v   = __attribute__((ext_vector_type(8))) short;
using f32x4 = __attribute__((ext_vector_type(4))) float;

__device__ __forceinline__ unsigned short f2bf(float f) {
    union { float f; unsigned int u; } c; c.f = f;
    unsigned int r = c.u + 0x7fffu + ((c.u >> 16) & 1u);   // RTN-even
    return (unsigned short)(r >> 16);
}
__device__ __forceinline__ float bf2f(unsigned short u) {
    union { unsigned int u; float f; } c; c.u = ((unsigned int)u) << 16;
    return c.f;
}

// async global->LDS, 16B per lane; LDS dest = wave-uniform base + lane*16
__device__ __forceinline__ void async16(const unsigned short* g, unsigned short* l) {
    __builtin_amdgcn_global_load_lds(
        (const __attribute__((address_space(1))) unsigned int*)g,
        (__attribute__((address_space(3))) unsigned int*)l, 16, 0, 0);
}

// ------------------ fused fp32->bf16 converts + vkws zero ------------------
__global__ __launch_bounds__(256)
void prep(const float* __restrict__ x, const float* __restrict__ wq,
          const float* __restrict__ wp, unsigned short* __restrict__ xb,
          unsigned short* __restrict__ wqb, unsigned short* __restrict__ wpb,
          float* __restrict__ vkws) {
    const int NX = 16777216 / 8, NQ = 3145728 / 8, NP = 1048576 / 8, NZ = 135168 / 8;
    int gid = blockIdx.x * 256 + threadIdx.x;
    const float* in; unsigned short* out; int i;
    if (gid < NX)                    { in = x;  out = xb;  i = gid * 8; }
    else if (gid < NX + NQ)          { in = wq; out = wqb; i = (gid - NX) * 8; }
    else if (gid < NX + NQ + NP)     { in = wp; out = wpb; i = (gid - NX - NQ) * 8; }
    else if (gid < NX + NQ + NP + NZ) {
        int z = (gid - NX - NQ - NP) * 8;
        f32x4 zero = {};
        *(f32x4*)(vkws + z) = zero; *(f32x4*)(vkws + z + 4) = zero;
        return;
    } else return;
    float4 a = *(const float4*)(in + i);
    float4 b = *(const float4*)(in + i + 4);
    us8 o;
    o[0] = f2bf(a.x); o[1] = f2bf(a.y); o[2] = f2bf(a.z); o[3] = f2bf(a.w);
    o[4] = f2bf(b.x); o[5] = f2bf(b.y); o[6] = f2bf(b.z); o[7] = f2bf(b.w);
    *(us8*)(out + i) = o;
}

// ----------------------- 256x256 8-phase GEMM core -------------------------
constexpr int HSZ = 128 * 64;            // elements per half-region (16 KiB)

#define FENCE() asm volatile("" ::: "memory")
#define BARX()  do { FENCE(); __builtin_amdgcn_s_barrier(); FENCE(); } while (0)
#define LGKM0() asm volatile("s_waitcnt lgkmcnt(0)" ::: "memory")

#define MFMA_QUAD(MB, NB)                                                    \
  do {                                                                       \
    __builtin_amdgcn_s_setprio(1);                                           \
    _Pragma("unroll")                                                        \
    for (int mi_ = 0; mi_ < 4; ++mi_)                                        \
      _Pragma("unroll")                                                      \
      for (int ni_ = 0; ni_ < 2; ++ni_)                                      \
        _Pragma("unroll")                                                    \
        for (int kk_ = 0; kk_ < 2; ++kk_)                                    \
          acc[(MB) + mi_][(NB) + ni_] =                                      \
              __builtin_amdgcn_mfma_f32_16x16x32_bf16(                       \
                  af[mi_][kk_], bf[(NB) + ni_][kk_],                         \
                  acc[(MB) + mi_][(NB) + ni_], 0, 0, 0);                     \
    __builtin_amdgcn_s_setprio(0);                                           \
  } while (0)

// stage one 128x64 half-tile (2 x global_load_lds per thread).
// LDS dest linear; global source pre-swizzled: element ((t&7)^(row&7))*8.
__device__ __forceinline__
void stage_half(const unsigned short* __restrict__ G, int rowBase, int kcol,
                unsigned short* ldsHalf, int row0, int esw, int wv) {
    async16(G + (size_t)(rowBase + row0) * 1024 + kcol + esw,
            ldsHalf + wv * 512);
    async16(G + (size_t)(rowBase + 64 + row0) * 1024 + kcol + esw,
            ldsHalf + 4096 + wv * 512);
}

// MODE 0: cols<1024 -> Q token-major bf16 (relu); cols>=1024 -> kvT.
// MODE 1: fp32 + bias.
template <int MODE>
__device__ __forceinline__
void gemm_core256(const unsigned short* __restrict__ A,
                  const unsigned short* __restrict__ Bt,
                  unsigned short* __restrict__ Cq,
                  unsigned short* __restrict__ kvT,
                  float* __restrict__ Cf, const float* __restrict__ bias,
                  int N, int tM, int tN, unsigned short* lds) {
    unsigned short* As = lds;                 // [2buf][2half][128][64]
    unsigned short* Bs = lds + 4 * HSZ;

    const int t    = threadIdx.x;
    const int lane = t & 63;
    const int wv   = t >> 6;
    const int wr   = wv >> 2;                 // 0..1 : A half / 128-row slab
    const int wc   = wv & 3;                  // 0..3 : 64-col slab
    const int mrow = lane & 15;
    const int kq   = lane >> 4;               // 0..3
    const int m7   = lane & 7;

    // staging thread map: row0 = t>>3 (0..63), swizzled source element
    const int row0 = t >> 3;
    const int esw  = ((t & 7) ^ (row0 & 7)) * 8;

    // swizzled k-slot element offsets for ds_read (kk=0/1)
    const int ks0 = ((0 * 4 + kq) ^ m7) * 8;
    const int ks1 = ((1 * 4 + kq) ^ m7) * 8;
    const int brow = (wc & 1) * 64;

    f32x4 acc[8][4] = {};
    s8v af[4][2], bf[4][2];

    constexpr int NT = 16;                    // K = 1024 = 16 x 64

    // prologue: tile0 (A0,A1,B0,B1) + tile1 (B0,B1,A0); tile1 A1 staged at g0.P1
    stage_half(A,  tM,       0,  As + 0 * HSZ, row0, esw, wv);
    stage_half(A,  tM + 128, 0,  As + 1 * HSZ, row0, esw, wv);
    stage_half(Bt, tN,       0,  Bs + 0 * HSZ, row0, esw, wv);
    stage_half(Bt, tN + 128, 0,  Bs + 1 * HSZ, row0, esw, wv);
    stage_half(Bt, tN,       64, Bs + 2 * HSZ, row0, esw, wv);
    stage_half(Bt, tN + 128, 64, Bs + 3 * HSZ, row0, esw, wv);
    stage_half(A,  tM,       64, As + 2 * HSZ, row0, esw, wv);
    asm volatile("s_waitcnt vmcnt(6)" ::: "memory");   // tile0 landed
    BARX();

    for (int g = 0; g < NT; ++g) {
        const int c = g & 1;
        const unsigned short* Ard = As + (c * 2 + wr) * HSZ;
        const unsigned short* Brd = Bs + (c * 2 + (wc >> 1)) * HSZ;
        const int kt1 = (g + 1 < NT ? g + 1 : NT - 1) * 64;
        const int kt2 = (g + 2 < NT ? g + 2 : NT - 1) * 64;

        // ---- P1: all B frags + A rows 0-63; stage A1(g+1) -> other buf ----
#pragma unroll
        for (int ni = 0; ni < 2; ++ni) {
            bf[ni][0] = *(const s8v*)&Brd[(brow + ni * 16 + mrow) * 64 + ks0];
            bf[ni][1] = *(const s8v*)&Brd[(brow + ni * 16 + mrow) * 64 + ks1];
        }
#pragma unroll
        for (int mi = 0; mi < 4; ++mi) {
            af[mi][0] = *(const s8v*)&Ard[(mi * 16 + mrow) * 64 + ks0];
            af[mi][1] = *(const s8v*)&Ard[(mi * 16 + mrow) * 64 + ks1];
        }
#pragma unroll
        for (int ni = 2; ni < 4; ++ni) {
            bf[ni][0] = *(const s8v*)&Brd[(brow + ni * 16 + mrow) * 64 + ks0];
            bf[ni][1] = *(const s8v*)&Brd[(brow + ni * 16 + mrow) * 64 + ks1];
        }
        stage_half(A, tM + 128, kt1, As + ((c ^ 1) * 2 + 1) * HSZ, row0, esw, wv);
        MFMA_QUAD(0, 0);
        LGKM0();                         // all buf-c reads of this phase done
        BARX();

        // ---- P2: stage B0(g+2) -> buf c (B reads drained at P1) ----
        stage_half(Bt, tN, kt2, Bs + (c * 2 + 0) * HSZ, row0, esw, wv);
        MFMA_QUAD(0, 2);
        BARX();

        // ---- P3: A rows 64-127; stage B1(g+2) -> buf c ----
#pragma unroll
        for (int mi = 0; mi < 4; ++mi) {
            af[mi][0] = *(const s8v*)&Ard[(64 + mi * 16 + mrow) * 64 + ks0];
            af[mi][1] = *(const s8v*)&Ard[(64 + mi * 16 + mrow) * 64 + ks1];
        }
        stage_half(Bt, tN + 128, kt2, Bs + (c * 2 + 1) * HSZ, row0, esw, wv);
        MFMA_QUAD(4, 0);
        LGKM0();                         // A reads drained -> A0 may be staged
        BARX();

        // ---- P4: stage A0(g+2) -> buf c; counted vmcnt (never 0) ----
        stage_half(A, tM, kt2, As + (c * 2 + 0) * HSZ, row0, esw, wv);
        MFMA_QUAD(4, 2);
        asm volatile("s_waitcnt vmcnt(6)" ::: "memory");  // tile g+1 landed
        BARX();
    }

    // ----------------------------- epilogue --------------------------------
    const int crow0 = kq * 4;
    const int ccol  = mrow;
    if (MODE == 0) {
        if (tN >= 1024) {
            const int b2  = tM >> 12;
            const int nb0 = (tM & 4095) + wr * 128;
#pragma unroll
            for (int mi = 0; mi < 8; ++mi) {
                const int nbase = nb0 + mi * 16 + crow0;
#pragma unroll
                for (int ni = 0; ni < 4; ++ni) {
                    const int col = tN + wc * 64 + ni * 16 + ccol;
                    f32x4 v = acc[mi][ni];
                    if (col < 2048) {
                        v[0] = fmaxf(v[0], 0.f); v[1] = fmaxf(v[1], 0.f);
                        v[2] = fmaxf(v[2], 0.f); v[3] = fmaxf(v[3], 0.f);
                    }
                    us4 o;
                    o[0] = f2bf(v[0]); o[1] = f2bf(v[1]);
                    o[2] = f2bf(v[2]); o[3] = f2bf(v[3]);
                    *(us4*)&kvT[((size_t)b2 * 2048 + (col - 1024)) * 4096 + nbase] = o;
                }
            }
        } else {
#pragma unroll
            for (int mi = 0; mi < 8; ++mi)
#pragma unroll
                for (int ni = 0; ni < 4; ++ni) {
                    const int row = tM + wr * 128 + mi * 16 + crow0;
                    const int col = tN + wc * 64 + ni * 16 + ccol;
#pragma unroll
                    for (int r2 = 0; r2 < 4; ++r2)
                        Cq[(size_t)(row + r2) * 1024 + col] =
                            f2bf(fmaxf(acc[mi][ni][r2], 0.f));
                }
        }
    } else {
#pragma unroll
        for (int mi = 0; mi < 8; ++mi)
#pragma unroll
            for (int ni = 0; ni < 4; ++ni) {
                const int row = tM + wr * 128 + mi * 16 + crow0;
                const int col = tN + wc * 64 + ni * 16 + ccol;
#pragma unroll
                for (int r2 = 0; r2 < 4; ++r2)
                    Cf[(size_t)(row + r2) * N + col] = acc[mi][ni][r2] + bias[col];
            }
    }
    // drain LDS-DMA before wave exit (LDS may be re-allocated to next block)
    asm volatile("s_waitcnt vmcnt(0)" ::: "memory");
}

// XCD-aware tile map: xcd = blk&7 owns an 8-M-tile stripe; N swept in panels
// of 4 (B-panel 2 MB stays L2-hot), tN fastest within panel.
__device__ __forceinline__ void xcd_map256(int blk, int MT, int& tM, int& tN) {
    const int xcd = blk & 7;
    const int i   = blk >> 3;
    const int MTx = MT >> 3;             // M-tiles per XCD (8)
    const int ppan = MTx * 4;            // blocks per 4-wide panel per XCD
    const int p   = i / ppan;
    const int i2  = i % ppan;
    tM = (xcd * MTx + (i2 >> 2)) * 256;
    tN = (p * 4 + (i2 & 3)) * 256;
}

__global__ __launch_bounds__(512, 2)
void gemm_qkv(const unsigned short* __restrict__ A,
              const unsigned short* __restrict__ Bt,
              unsigned short* __restrict__ Cq, unsigned short* __restrict__ kvT,
              int M, int N) {
    extern __shared__ unsigned short lds[];
    int tM, tN;
    xcd_map256(blockIdx.x, M >> 8, tM, tN);
    gemm_core256<0>(A, Bt, Cq, kvT, nullptr, nullptr, N, tM, tN, lds);
}

__global__ __launch_bounds__(512, 2)
void gemm_proj(const unsigned short* __restrict__ A,
               const unsigned short* __restrict__ Bt,
               float* __restrict__ C, const float* __restrict__ bias,
               int M, int N) {
    extern __shared__ unsigned short lds[];
    int tM, tN;
    xcd_map256(blockIdx.x, M >> 8, tM, tN);
    gemm_core256<1>(A, Bt, nullptr, nullptr, C, bias, N, tM, tN, lds);
}

// ---------------- vk = Vpad @ reluK^T via MFMA over kvT --------------------
__global__ __launch_bounds__(256)
void lite_vk(const unsigned short* __restrict__ kvT, float* __restrict__ vkws) {
    const int bh = blockIdx.x, ck = blockIdx.y;
    const int b = bh >> 5, h = bh & 31;
    const int S = 136;
    __shared__ unsigned short Ks[32 * S];
    __shared__ unsigned short Vs[32 * S];
    __shared__ float Rs[4][1088];
    const int t = threadIdx.x, lane = t & 63, wv = t >> 6;
    const unsigned short* Kp = kvT + ((size_t)b * 2048 + h * 32) * 4096 + ck * 512;
    const unsigned short* Vp = kvT + ((size_t)b * 2048 + 1024 + h * 32) * 4096 + ck * 512;
    const int sr = t >> 3, ss = (t & 7) * 16;
    f32x4 acc00 = {}, acc01 = {}, acc10 = {}, acc11 = {}, accO0 = {}, accO1 = {};
    s8v ones;
#pragma unroll
    for (int j = 0; j < 8; ++j) ones[j] = (short)0x3F80;
    const int mrow = lane & 15, kq = (lane >> 4) * 8;

    for (int tile = 0; tile < 4; ++tile) {
        int go = tile * 128 + ss;
        us8 k0v = *(const us8*)(Kp + (size_t)sr * 4096 + go);
        us8 k1v = *(const us8*)(Kp + (size_t)sr * 4096 + go + 8);
        us8 v0v = *(const us8*)(Vp + (size_t)sr * 4096 + go);
        us8 v1v = *(const us8*)(Vp + (size_t)sr * 4096 + go + 8);
        __syncthreads();
        *(us8*)&Ks[sr * S + ss]     = k0v;
        *(us8*)&Ks[sr * S + ss + 8] = k1v;
        *(us8*)&Vs[sr * S + ss]     = v0v;
        *(us8*)&Vs[sr * S + ss + 8] = v1v;
        __syncthreads();
        int ko = wv * 32 + kq;
        s8v a0 = *(const s8v*)&Vs[(mrow)      * S + ko];
        s8v a1 = *(const s8v*)&Vs[(16 + mrow) * S + ko];
        s8v b0 = *(const s8v*)&Ks[(mrow)      * S + ko];
        s8v b1 = *(const s8v*)&Ks[(16 + mrow) * S + ko];
        acc00 = __builtin_amdgcn_mfma_f32_16x16x32_bf16(a0, b0, acc00, 0, 0, 0);
        acc01 = __builtin_amdgcn_mfma_f32_16x16x32_bf16(a0, b1, acc01, 0, 0, 0);
        acc10 = __builtin_amdgcn_mfma_f32_16x16x32_bf16(a1, b0, acc10, 0, 0, 0);
        acc11 = __builtin_amdgcn_mfma_f32_16x16x32_bf16(a1, b1, acc11, 0, 0, 0);
        accO0 = __builtin_amdgcn_mfma_f32_16x16x32_bf16(ones, b0, accO0, 0, 0, 0);
        accO1 = __builtin_amdgcn_mfma_f32_16x16x32_bf16(ones, b1, accO1, 0, 0, 0);
    }

    const int ccol = lane & 15, crow = (lane >> 4) * 4;
    float* R = Rs[wv];
#pragma unroll
    for (int r2 = 0; r2 < 4; ++r2) {
        R[(crow + r2) * 32 + ccol]           = acc00[r2];
        R[(crow + r2) * 32 + 16 + ccol]      = acc01[r2];
        R[(16 + crow + r2) * 32 + ccol]      = acc10[r2];
        R[(16 + crow + r2) * 32 + 16 + ccol] = acc11[r2];
    }
    if ((lane >> 4) == 0) {
        R[1024 + ccol]      = accO0[0];
        R[1024 + 16 + ccol] = accO1[0];
    }
    __syncthreads();
    float* vkb = vkws + bh * (33 * 32);
    for (int i = t; i < 1056; i += 256) {
        float s = Rs[0][i] + Rs[1][i] + Rs[2][i] + Rs[3][i];
        atomicAdd(&vkb[i], s);
    }
}

// --------------- y = (vk @ reluQ) / pad-row, MFMA K=32 ---------------------
__global__ __launch_bounds__(256)
void lite_apply(const unsigned short* __restrict__ qb,
                const float* __restrict__ vkws,
                unsigned short* __restrict__ yb) {
    const int bh = blockIdx.x, nb = blockIdx.y;
    const int b = bh >> 5, h = bh & 31;
    __shared__ unsigned short vkh[48 * 32];
    __shared__ unsigned short vkl[48 * 32];
    const int t = threadIdx.x;
    for (int i = t; i < 48 * 32; i += 256) {
        float v = (i < 33 * 32) ? vkws[bh * (33 * 32) + i] : 0.f;
        unsigned short hi = f2bf(v);
        vkh[i] = hi;
        vkl[i] = f2bf(v - bf2f(hi));
    }
    __syncthreads();

    const int lane = t & 63, wv = t >> 6;
    const int col = lane & 15, quad = lane >> 4;
    s8v b0h = *(const s8v*)&vkh[(col)      * 32 + quad * 8];
    s8v b0l = *(const s8v*)&vkl[(col)      * 32 + quad * 8];
    s8v b1h = *(const s8v*)&vkh[(16 + col) * 32 + quad * 8];
    s8v b1l = *(const s8v*)&vkl[(16 + col) * 32 + quad * 8];
    s8v b2h = *(const s8v*)&vkh[(32 + col) * 32 + quad * 8];
    s8v b2l = *(const s8v*)&vkl[(32 + col) * 32 + quad * 8];

    const int ntile = nb * 256 + wv * 64;
#pragma unroll
    for (int mi = 0; mi < 4; ++mi) {
        int tok = ntile + mi * 16 + col;
        const unsigned short* qp =
            qb + (size_t)(b * 4096 + tok) * 1024 + h * 32 + quad * 8;
        s8v a = *(const s8v*)qp;
        f32x4 n0 = {}, n1 = {}, dd = {};
        n0 = __builtin_amdgcn_mfma_f32_16x16x32_bf16(b0h, a, n0, 0, 0, 0);
        n0 = __builtin_amdgcn_mfma_f32_16x16x32_bf16(b0l, a, n0, 0, 0, 0);
        n1 = __builtin_amdgcn_mfma_f32_16x16x32_bf16(b1h, a, n1, 0, 0, 0);
        n1 = __builtin_amdgcn_mfma_f32_16x16x32_bf16(b1l, a, n1, 0, 0, 0);
        dd = __builtin_amdgcn_mfma_f32_16x16x32_bf16(b2h, a, dd, 0, 0, 0);
        dd = __builtin_amdgcn_mfma_f32_16x16x32_bf16(b2l, a, dd, 0, 0, 0);
        float den  = __shfl(dd[0], col, 64);
        float rinv = 1.f / (den + 1e-15f);
        us4 o0, o1;
#pragma unroll
        for (int r = 0; r < 4; ++r) {
            o0[r] = f2bf(n0[r] * rinv);
            o1[r] = f2bf(n1[r] * rinv);
        }
        size_t o = (size_t)(b * 4096 + tok) * 1024 + h * 32;
        *(us4*)&yb[o + quad * 4]      = o0;
        *(us4*)&yb[o + 16 + quad * 4] = o1;
    }
}

// ---------------------------------------------------------------------------
extern "C" void kernel_launch(void* const* d_in, const int* in_sizes, int n_in,
                              void* d_out, int out_size, void* d_ws, size_t ws_size,
                              hipStream_t stream) {
    const float* x     = (const float*)d_in[0];   // (4,4096,1024)
    const float* Wqkv  = (const float*)d_in[1];   // (3072,1024)
    const float* Wproj = (const float*)d_in[2];   // (1024,1024)
    const float* bproj = (const float*)d_in[3];   // (1024,)
    float* out = (float*)d_out;                   // (4,4096,1024) fp32

    const int M = 16384, Cdim = 1024, O1 = 3072;

    unsigned short* xb     = (unsigned short*)d_ws;
    unsigned short* wqkvb  = xb + (size_t)M * Cdim;
    unsigned short* wprojb = wqkvb + (size_t)O1 * Cdim;
    unsigned short* qb     = wprojb + (size_t)Cdim * Cdim;        // Q token-major
    unsigned short* kvT    = qb + (size_t)M * Cdim;               // [4][2048][4096]
    unsigned short* ybuf   = kvT + (size_t)4 * 2048 * 4096;
    float* vkws            = (float*)(ybuf + (size_t)M * Cdim);
    // ws use: ~176 MB

    static int attr_done = 0;
    if (!attr_done) {
        hipFuncSetAttribute((const void*)gemm_qkv,
                            hipFuncAttributeMaxDynamicSharedMemorySize, 131072);
        hipFuncSetAttribute((const void*)gemm_proj,
                            hipFuncAttributeMaxDynamicSharedMemorySize, 131072);
        attr_done = 1;
    }

    const int PREP_GROUPS = (16777216 + 3145728 + 1048576 + 135168) / 8;
    prep<<<(PREP_GROUPS + 255) / 256, 256, 0, stream>>>(
        x, Wqkv, Wproj, xb, wqkvb, wprojb, vkws);

    gemm_qkv<<<(M / 256) * (O1 / 256), 512, 131072, stream>>>(
        xb, wqkvb, qb, kvT, M, O1);

    lite_vk<<<dim3(128, 8), 256, 0, stream>>>(kvT, vkws);
    lite_apply<<<dim3(128, 16), 256, 0, stream>>>(qb, vkws, ybuf);

    gemm_proj<<<(M / 256) * (Cdim / 256), 512, 131072, stream>>>(
        ybuf, wprojb, out, bproj, M, Cdim);
}

// Round 2
// 309.762 us; speedup vs baseline: 1.0760x; 1.0057x over previous
//
#include <hip/hip_runtime.h>

// ---------------------------------------------------------------------------
// LiteMLA: B=4, N=4096, C=1024, D=32, h=32 heads.
//   qkv = x @ W_qkv^T            (16384 x 3072, K=1024)   [relu on q,k cols]
//   per (b,h): vk[d,e] = sum_n Vpad[d,n]*reluK[e,n]   (33x32, reduce N=4096)
//              y[d,n]  = (sum_e vk[d,e]*reluQ[e,n]) / (sum_e vk[32,e]*reluQ[e,n] + eps)
//   out = y @ W_proj^T + b_proj  (16384 x 1024, K=1024)
//
// GEMMs: 256x256 tile, BK=64, 8 waves (512 thr), 128 KiB dynamic LDS,
// m201-faithful 4-phase/K-tile schedule:
//   phase = { ds_read subtile ; stage 1 half-tile ; s_barrier ; lgkmcnt(0) ;
//             setprio(1) 16xMFMA setprio(0) ; s_barrier }
// ds_reads spread 12/4/4+8/0 via ni>>1 -> B-half mapping (each wave reads
// both B halves). vmcnt(6) once per K-tile at P4 (3 half-tiles in flight).
// Race-freedom: reads of a region are issued in phase <= i and drained by
// phase i's lgkm0 + 2nd barrier; every stage into that region is in a later
// phase. A1(g+1)@P1 -> other buf (reads ended g-1.P3). vmcnt(6)@P4 retires
// exactly through tile g+1's last half before g+1.P1 reads it.
// LDS slot swizzle (kk*4+kq)^(row&7): pre-swizzled global source, XOR'd
// ds_read address (linear DMA dest) -- unchanged from verified kernel.
// ---------------------------------------------------------------------------

using us8   = __attribute__((ext_vector_type(8))) unsigned short;
using us4   = __attribute__((ext_vector_type(4))) unsigned short;
using s8v   = __attribute__((ext_vector_type(8))) short;
using f32x4 = __attribute__((ext_vector_type(4))) float;

__device__ __forceinline__ unsigned short f2bf(float f) {
    union { float f; unsigned int u; } c; c.f = f;
    unsigned int r = c.u + 0x7fffu + ((c.u >> 16) & 1u);   // RTN-even
    return (unsigned short)(r >> 16);
}
__device__ __forceinline__ float bf2f(unsigned short u) {
    union { unsigned int u; float f; } c; c.u = ((unsigned int)u) << 16;
    return c.f;
}

// async global->LDS, 16B per lane; LDS dest = wave-uniform base + lane*16
__device__ __forceinline__ void async16(const unsigned short* g, unsigned short* l) {
    __builtin_amdgcn_global_load_lds(
        (const __attribute__((address_space(1))) unsigned int*)g,
        (__attribute__((address_space(3))) unsigned int*)l, 16, 0, 0);
}

// ------------------ fused fp32->bf16 converts + vkws zero ------------------
__global__ __launch_bounds__(256)
void prep(const float* __restrict__ x, const float* __restrict__ wq,
          const float* __restrict__ wp, unsigned short* __restrict__ xb,
          unsigned short* __restrict__ wqb, unsigned short* __restrict__ wpb,
          float* __restrict__ vkws) {
    const int NX = 16777216 / 8, NQ = 3145728 / 8, NP = 1048576 / 8, NZ = 135168 / 8;
    int gid = blockIdx.x * 256 + threadIdx.x;
    const float* in; unsigned short* out; int i;
    if (gid < NX)                    { in = x;  out = xb;  i = gid * 8; }
    else if (gid < NX + NQ)          { in = wq; out = wqb; i = (gid - NX) * 8; }
    else if (gid < NX + NQ + NP)     { in = wp; out = wpb; i = (gid - NX - NQ) * 8; }
    else if (gid < NX + NQ + NP + NZ) {
        int z = (gid - NX - NQ - NP) * 8;
        f32x4 zero = {};
        *(f32x4*)(vkws + z) = zero; *(f32x4*)(vkws + z + 4) = zero;
        return;
    } else return;
    float4 a = *(const float4*)(in + i);
    float4 b = *(const float4*)(in + i + 4);
    us8 o;
    o[0] = f2bf(a.x); o[1] = f2bf(a.y); o[2] = f2bf(a.z); o[3] = f2bf(a.w);
    o[4] = f2bf(b.x); o[5] = f2bf(b.y); o[6] = f2bf(b.z); o[7] = f2bf(b.w);
    *(us8*)(out + i) = o;
}

// ----------------------- 256x256 4-phase GEMM core -------------------------
constexpr int HSZ = 128 * 64;            // elements per half-region (16 KiB)

#define FENCE() asm volatile("" ::: "memory")
#define BARX()  do { FENCE(); __builtin_amdgcn_s_barrier(); FENCE(); } while (0)
#define LGKM0() asm volatile("s_waitcnt lgkmcnt(0)" ::: "memory")

#define MFMA_QUAD(MB, NB)                                                    \
  do {                                                                       \
    __builtin_amdgcn_s_setprio(1);                                           \
    _Pragma("unroll")                                                        \
    for (int mi_ = 0; mi_ < 4; ++mi_)                                        \
      _Pragma("unroll")                                                      \
      for (int ni_ = 0; ni_ < 2; ++ni_)                                      \
        _Pragma("unroll")                                                    \
        for (int kk_ = 0; kk_ < 2; ++kk_)                                    \
          acc[(MB) + mi_][(NB) + ni_] =                                      \
              __builtin_amdgcn_mfma_f32_16x16x32_bf16(                       \
                  af[mi_][kk_], bf[(NB) + ni_][kk_],                         \
                  acc[(MB) + mi_][(NB) + ni_], 0, 0, 0);                     \
    __builtin_amdgcn_s_setprio(0);                                           \
  } while (0)

// stage one 128x64 half-tile (2 x global_load_lds per thread).
// LDS dest linear; global source pre-swizzled: element ((t&7)^(row&7))*8.
__device__ __forceinline__
void stage_half(const unsigned short* __restrict__ G, int rowBase, int kcol,
                unsigned short* ldsHalf, int row0, int esw, int wv) {
    async16(G + (size_t)(rowBase + row0) * 1024 + kcol + esw,
            ldsHalf + wv * 512);
    async16(G + (size_t)(rowBase + 64 + row0) * 1024 + kcol + esw,
            ldsHalf + 4096 + wv * 512);
}

// MODE 0: cols<1024 -> Q token-major bf16 (relu); cols>=1024 -> kvT.
// MODE 1: fp32 + bias.
template <int MODE>
__device__ __forceinline__
void gemm_core256(const unsigned short* __restrict__ A,
                  const unsigned short* __restrict__ Bt,
                  unsigned short* __restrict__ Cq,
                  unsigned short* __restrict__ kvT,
                  float* __restrict__ Cf, const float* __restrict__ bias,
                  int N, int tM, int tN, unsigned short* lds) {
    unsigned short* As = lds;                 // [2buf][2half][128][64]
    unsigned short* Bs = lds + 4 * HSZ;

    const int t    = threadIdx.x;
    const int lane = t & 63;
    const int wv   = t >> 6;
    const int wr   = wv >> 2;                 // 0..1 : A 128-row slab
    const int wc   = wv & 3;                  // 0..3 : 32-row group in each B half
    const int mrow = lane & 15;
    const int kq   = lane >> 4;               // 0..3
    const int m7   = lane & 7;

    // staging thread map: row0 = t>>3 (0..63), swizzled source element
    const int row0 = t >> 3;
    const int esw  = ((t & 7) ^ (row0 & 7)) * 8;

    // swizzled k-slot element offsets for ds_read (kk=0/1)
    const int ks0 = ((0 * 4 + kq) ^ m7) * 8;
    const int ks1 = ((1 * 4 + kq) ^ m7) * 8;
    const int browB = wc * 32;                // row group inside each B half

    f32x4 acc[8][4] = {};
    s8v af[4][2], bf[4][2];

    constexpr int NT = 16;                    // K = 1024 = 16 x 64

    // prologue: tile0 (A0,A1,B0,B1) + tile1 (B0,B1,A0); tile1 A1 staged at g0.P1
    stage_half(A,  tM,       0,  As + 0 * HSZ, row0, esw, wv);
    stage_half(A,  tM + 128, 0,  As + 1 * HSZ, row0, esw, wv);
    stage_half(Bt, tN,       0,  Bs + 0 * HSZ, row0, esw, wv);
    stage_half(Bt, tN + 128, 0,  Bs + 1 * HSZ, row0, esw, wv);
    stage_half(Bt, tN,       64, Bs + 2 * HSZ, row0, esw, wv);
    stage_half(Bt, tN + 128, 64, Bs + 3 * HSZ, row0, esw, wv);
    stage_half(A,  tM,       64, As + 2 * HSZ, row0, esw, wv);
    asm volatile("s_waitcnt vmcnt(6)" ::: "memory");   // tile0 landed
    BARX();

    for (int g = 0; g < NT; ++g) {
        const int c = g & 1;
        const unsigned short* Ard  = As + (c * 2 + wr) * HSZ;
        const unsigned short* B0rd = Bs + (c * 2 + 0) * HSZ;
        const unsigned short* B1rd = Bs + (c * 2 + 1) * HSZ;
        const int kt1 = (g + 1 < NT ? g + 1 : NT - 1) * 64;
        const int kt2 = (g + 2 < NT ? g + 2 : NT - 1) * 64;

        // ---- P1: read bf[0..1](half0) + af M0 ; stage A1(g+1) -> buf c^1 --
        bf[0][0] = *(const s8v*)&B0rd[(browB + mrow) * 64 + ks0];
        bf[0][1] = *(const s8v*)&B0rd[(browB + mrow) * 64 + ks1];
        bf[1][0] = *(const s8v*)&B0rd[(browB + 16 + mrow) * 64 + ks0];
        bf[1][1] = *(const s8v*)&B0rd[(browB + 16 + mrow) * 64 + ks1];
#pragma unroll
        for (int mi = 0; mi < 4; ++mi) {
            af[mi][0] = *(const s8v*)&Ard[(mi * 16 + mrow) * 64 + ks0];
            af[mi][1] = *(const s8v*)&Ard[(mi * 16 + mrow) * 64 + ks1];
        }
        stage_half(A, tM + 128, kt1, As + ((c ^ 1) * 2 + 1) * HSZ, row0, esw, wv);
        BARX();
        LGKM0();
        MFMA_QUAD(0, 0);
        BARX();

        // ---- P2: read bf[2..3](half1) ; stage B0(g+2) -> buf c ------------
        bf[2][0] = *(const s8v*)&B1rd[(browB + mrow) * 64 + ks0];
        bf[2][1] = *(const s8v*)&B1rd[(browB + mrow) * 64 + ks1];
        bf[3][0] = *(const s8v*)&B1rd[(browB + 16 + mrow) * 64 + ks0];
        bf[3][1] = *(const s8v*)&B1rd[(browB + 16 + mrow) * 64 + ks1];
        stage_half(Bt, tN, kt2, Bs + (c * 2 + 0) * HSZ, row0, esw, wv);
        BARX();
        LGKM0();
        MFMA_QUAD(0, 2);
        BARX();

        // ---- P3: read af M1 ; stage B1(g+2) -> buf c ----------------------
#pragma unroll
        for (int mi = 0; mi < 4; ++mi) {
            af[mi][0] = *(const s8v*)&Ard[(64 + mi * 16 + mrow) * 64 + ks0];
            af[mi][1] = *(const s8v*)&Ard[(64 + mi * 16 + mrow) * 64 + ks1];
        }
        stage_half(Bt, tN + 128, kt2, Bs + (c * 2 + 1) * HSZ, row0, esw, wv);
        BARX();
        LGKM0();
        MFMA_QUAD(4, 0);
        BARX();

        // ---- P4: stage A0(g+2) -> buf c ; counted vmcnt (never 0) ---------
        stage_half(A, tM, kt2, As + (c * 2 + 0) * HSZ, row0, esw, wv);
        BARX();
        MFMA_QUAD(4, 2);
        asm volatile("s_waitcnt vmcnt(6)" ::: "memory");  // tile g+1 landed
        BARX();
    }

    // ----------------------------- epilogue --------------------------------
    const int crow0 = kq * 4;
    const int ccol  = mrow;
    if (MODE == 0) {
        if (tN >= 1024) {
            const int b2  = tM >> 12;
            const int nb0 = (tM & 4095) + wr * 128;
#pragma unroll
            for (int mi = 0; mi < 8; ++mi) {
                const int nbase = nb0 + mi * 16 + crow0;
#pragma unroll
                for (int ni = 0; ni < 4; ++ni) {
                    const int col = tN + (ni >> 1) * 128 + wc * 32 + (ni & 1) * 16 + ccol;
                    f32x4 v = acc[mi][ni];
                    if (col < 2048) {
                        v[0] = fmaxf(v[0], 0.f); v[1] = fmaxf(v[1], 0.f);
                        v[2] = fmaxf(v[2], 0.f); v[3] = fmaxf(v[3], 0.f);
                    }
                    us4 o;
                    o[0] = f2bf(v[0]); o[1] = f2bf(v[1]);
                    o[2] = f2bf(v[2]); o[3] = f2bf(v[3]);
                    *(us4*)&kvT[((size_t)b2 * 2048 + (col - 1024)) * 4096 + nbase] = o;
                }
            }
        } else {
#pragma unroll
            for (int mi = 0; mi < 8; ++mi)
#pragma unroll
                for (int ni = 0; ni < 4; ++ni) {
                    const int row = tM + wr * 128 + mi * 16 + crow0;
                    const int col = tN + (ni >> 1) * 128 + wc * 32 + (ni & 1) * 16 + ccol;
#pragma unroll
                    for (int r2 = 0; r2 < 4; ++r2)
                        Cq[(size_t)(row + r2) * 1024 + col] =
                            f2bf(fmaxf(acc[mi][ni][r2], 0.f));
                }
        }
    } else {
#pragma unroll
        for (int mi = 0; mi < 8; ++mi)
#pragma unroll
            for (int ni = 0; ni < 4; ++ni) {
                const int row = tM + wr * 128 + mi * 16 + crow0;
                const int col = tN + (ni >> 1) * 128 + wc * 32 + (ni & 1) * 16 + ccol;
#pragma unroll
                for (int r2 = 0; r2 < 4; ++r2)
                    Cf[(size_t)(row + r2) * N + col] = acc[mi][ni][r2] + bias[col];
            }
    }
    // drain LDS-DMA before wave exit (LDS may be re-allocated to next block)
    asm volatile("s_waitcnt vmcnt(0)" ::: "memory");
}

// XCD-aware tile map: xcd = blk&7 owns an 8-M-tile stripe; N swept in panels
// of 4 (B-panel 2 MB stays L2-hot), tN fastest within panel.
__device__ __forceinline__ void xcd_map256(int blk, int MT, int& tM, int& tN) {
    const int xcd = blk & 7;
    const int i   = blk >> 3;
    const int MTx = MT >> 3;             // M-tiles per XCD (8)
    const int ppan = MTx * 4;            // blocks per 4-wide panel per XCD
    const int p   = i / ppan;
    const int i2  = i % ppan;
    tM = (xcd * MTx + (i2 >> 2)) * 256;
    tN = (p * 4 + (i2 & 3)) * 256;
}

__global__ __launch_bounds__(512, 2)
void gemm_qkv(const unsigned short* __restrict__ A,
              const unsigned short* __restrict__ Bt,
              unsigned short* __restrict__ Cq, unsigned short* __restrict__ kvT,
              int M, int N) {
    extern __shared__ unsigned short lds[];
    int tM, tN;
    xcd_map256(blockIdx.x, M >> 8, tM, tN);
    gemm_core256<0>(A, Bt, Cq, kvT, nullptr, nullptr, N, tM, tN, lds);
}

__global__ __launch_bounds__(512, 2)
void gemm_proj(const unsigned short* __restrict__ A,
               const unsigned short* __restrict__ Bt,
               float* __restrict__ C, const float* __restrict__ bias,
               int M, int N) {
    extern __shared__ unsigned short lds[];
    int tM, tN;
    xcd_map256(blockIdx.x, M >> 8, tM, tN);
    gemm_core256<1>(A, Bt, nullptr, nullptr, C, bias, N, tM, tN, lds);
}

// ---------------- vk = Vpad @ reluK^T via MFMA over kvT --------------------
__global__ __launch_bounds__(256)
void lite_vk(const unsigned short* __restrict__ kvT, float* __restrict__ vkws) {
    const int bh = blockIdx.x, ck = blockIdx.y;
    const int b = bh >> 5, h = bh & 31;
    const int S = 136;
    __shared__ unsigned short Ks[32 * S];
    __shared__ unsigned short Vs[32 * S];
    __shared__ float Rs[4][1088];
    const int t = threadIdx.x, lane = t & 63, wv = t >> 6;
    const unsigned short* Kp = kvT + ((size_t)b * 2048 + h * 32) * 4096 + ck * 512;
    const unsigned short* Vp = kvT + ((size_t)b * 2048 + 1024 + h * 32) * 4096 + ck * 512;
    const int sr = t >> 3, ss = (t & 7) * 16;
    f32x4 acc00 = {}, acc01 = {}, acc10 = {}, acc11 = {}, accO0 = {}, accO1 = {};
    s8v ones;
#pragma unroll
    for (int j = 0; j < 8; ++j) ones[j] = (short)0x3F80;
    const int mrow = lane & 15, kq = (lane >> 4) * 8;

    for (int tile = 0; tile < 4; ++tile) {
        int go = tile * 128 + ss;
        us8 k0v = *(const us8*)(Kp + (size_t)sr * 4096 + go);
        us8 k1v = *(const us8*)(Kp + (size_t)sr * 4096 + go + 8);
        us8 v0v = *(const us8*)(Vp + (size_t)sr * 4096 + go);
        us8 v1v = *(const us8*)(Vp + (size_t)sr * 4096 + go + 8);
        __syncthreads();
        *(us8*)&Ks[sr * S + ss]     = k0v;
        *(us8*)&Ks[sr * S + ss + 8] = k1v;
        *(us8*)&Vs[sr * S + ss]     = v0v;
        *(us8*)&Vs[sr * S + ss + 8] = v1v;
        __syncthreads();
        int ko = wv * 32 + kq;
        s8v a0 = *(const s8v*)&Vs[(mrow)      * S + ko];
        s8v a1 = *(const s8v*)&Vs[(16 + mrow) * S + ko];
        s8v b0 = *(const s8v*)&Ks[(mrow)      * S + ko];
        s8v b1 = *(const s8v*)&Ks[(16 + mrow) * S + ko];
        acc00 = __builtin_amdgcn_mfma_f32_16x16x32_bf16(a0, b0, acc00, 0, 0, 0);
        acc01 = __builtin_amdgcn_mfma_f32_16x16x32_bf16(a0, b1, acc01, 0, 0, 0);
        acc10 = __builtin_amdgcn_mfma_f32_16x16x32_bf16(a1, b0, acc10, 0, 0, 0);
        acc11 = __builtin_amdgcn_mfma_f32_16x16x32_bf16(a1, b1, acc11, 0, 0, 0);
        accO0 = __builtin_amdgcn_mfma_f32_16x16x32_bf16(ones, b0, accO0, 0, 0, 0);
        accO1 = __builtin_amdgcn_mfma_f32_16x16x32_bf16(ones, b1, accO1, 0, 0, 0);
    }

    const int ccol = lane & 15, crow = (lane >> 4) * 4;
    float* R = Rs[wv];
#pragma unroll
    for (int r2 = 0; r2 < 4; ++r2) {
        R[(crow + r2) * 32 + ccol]           = acc00[r2];
        R[(crow + r2) * 32 + 16 + ccol]      = acc01[r2];
        R[(16 + crow + r2) * 32 + ccol]      = acc10[r2];
        R[(16 + crow + r2) * 32 + 16 + ccol] = acc11[r2];
    }
    if ((lane >> 4) == 0) {
        R[1024 + ccol]      = accO0[0];
        R[1024 + 16 + ccol] = accO1[0];
    }
    __syncthreads();
    float* vkb = vkws + bh * (33 * 32);
    for (int i = t; i < 1056; i += 256) {
        float s = Rs[0][i] + Rs[1][i] + Rs[2][i] + Rs[3][i];
        atomicAdd(&vkb[i], s);
    }
}

// --------------- y = (vk @ reluQ) / pad-row, MFMA K=32 ---------------------
__global__ __launch_bounds__(256)
void lite_apply(const unsigned short* __restrict__ qb,
                const float* __restrict__ vkws,
                unsigned short* __restrict__ yb) {
    const int bh = blockIdx.x, nb = blockIdx.y;
    const int b = bh >> 5, h = bh & 31;
    __shared__ unsigned short vkh[48 * 32];
    __shared__ unsigned short vkl[48 * 32];
    const int t = threadIdx.x;
    for (int i = t; i < 48 * 32; i += 256) {
        float v = (i < 33 * 32) ? vkws[bh * (33 * 32) + i] : 0.f;
        unsigned short hi = f2bf(v);
        vkh[i] = hi;
        vkl[i] = f2bf(v - bf2f(hi));
    }
    __syncthreads();

    const int lane = t & 63, wv = t >> 6;
    const int col = lane & 15, quad = lane >> 4;
    s8v b0h = *(const s8v*)&vkh[(col)      * 32 + quad * 8];
    s8v b0l = *(const s8v*)&vkl[(col)      * 32 + quad * 8];
    s8v b1h = *(const s8v*)&vkh[(16 + col) * 32 + quad * 8];
    s8v b1l = *(const s8v*)&vkl[(16 + col) * 32 + quad * 8];
    s8v b2h = *(const s8v*)&vkh[(32 + col) * 32 + quad * 8];
    s8v b2l = *(const s8v*)&vkl[(32 + col) * 32 + quad * 8];

    const int ntile = nb * 256 + wv * 64;
#pragma unroll
    for (int mi = 0; mi < 4; ++mi) {
        int tok = ntile + mi * 16 + col;
        const unsigned short* qp =
            qb + (size_t)(b * 4096 + tok) * 1024 + h * 32 + quad * 8;
        s8v a = *(const s8v*)qp;
        f32x4 n0 = {}, n1 = {}, dd = {};
        n0 = __builtin_amdgcn_mfma_f32_16x16x32_bf16(b0h, a, n0, 0, 0, 0);
        n0 = __builtin_amdgcn_mfma_f32_16x16x32_bf16(b0l, a, n0, 0, 0, 0);
        n1 = __builtin_amdgcn_mfma_f32_16x16x32_bf16(b1h, a, n1, 0, 0, 0);
        n1 = __builtin_amdgcn_mfma_f32_16x16x32_bf16(b1l, a, n1, 0, 0, 0);
        dd = __builtin_amdgcn_mfma_f32_16x16x32_bf16(b2h, a, dd, 0, 0, 0);
        dd = __builtin_amdgcn_mfma_f32_16x16x32_bf16(b2l, a, dd, 0, 0, 0);
        float den  = __shfl(dd[0], col, 64);
        float rinv = 1.f / (den + 1e-15f);
        us4 o0, o1;
#pragma unroll
        for (int r = 0; r < 4; ++r) {
            o0[r] = f2bf(n0[r] * rinv);
            o1[r] = f2bf(n1[r] * rinv);
        }
        size_t o = (size_t)(b * 4096 + tok) * 1024 + h * 32;
        *(us4*)&yb[o + quad * 4]      = o0;
        *(us4*)&yb[o + 16 + quad * 4] = o1;
    }
}

// ---------------------------------------------------------------------------
extern "C" void kernel_launch(void* const* d_in, const int* in_sizes, int n_in,
                              void* d_out, int out_size, void* d_ws, size_t ws_size,
                              hipStream_t stream) {
    const float* x     = (const float*)d_in[0];   // (4,4096,1024)
    const float* Wqkv  = (const float*)d_in[1];   // (3072,1024)
    const float* Wproj = (const float*)d_in[2];   // (1024,1024)
    const float* bproj = (const float*)d_in[3];   // (1024,)
    float* out = (float*)d_out;                   // (4,4096,1024) fp32

    const int M = 16384, Cdim = 1024, O1 = 3072;

    unsigned short* xb     = (unsigned short*)d_ws;
    unsigned short* wqkvb  = xb + (size_t)M * Cdim;
    unsigned short* wprojb = wqkvb + (size_t)O1 * Cdim;
    unsigned short* qb     = wprojb + (size_t)Cdim * Cdim;        // Q token-major
    unsigned short* kvT    = qb + (size_t)M * Cdim;               // [4][2048][4096]
    unsigned short* ybuf   = kvT + (size_t)4 * 2048 * 4096;
    float* vkws            = (float*)(ybuf + (size_t)M * Cdim);
    // ws use: ~176 MB

    static int attr_done = 0;
    if (!attr_done) {
        hipFuncSetAttribute((const void*)gemm_qkv,
                            hipFuncAttributeMaxDynamicSharedMemorySize, 131072);
        hipFuncSetAttribute((const void*)gemm_proj,
                            hipFuncAttributeMaxDynamicSharedMemorySize, 131072);
        attr_done = 1;
    }

    const int PREP_GROUPS = (16777216 + 3145728 + 1048576 + 135168) / 8;
    prep<<<(PREP_GROUPS + 255) / 256, 256, 0, stream>>>(
        x, Wqkv, Wproj, xb, wqkvb, wprojb, vkws);

    gemm_qkv<<<(M / 256) * (O1 / 256), 512, 131072, stream>>>(
        xb, wqkvb, qb, kvT, M, O1);

    lite_vk<<<dim3(128, 8), 256, 0, stream>>>(kvT, vkws);
    lite_apply<<<dim3(128, 16), 256, 0, stream>>>(qb, vkws, ybuf);

    gemm_proj<<<(M / 256) * (Cdim / 256), 512, 131072, stream>>>(
        ybuf, wprojb, out, bproj, M, Cdim);
}